// Round 1
// baseline (1858.088 us; speedup 1.0000x reference)
//
#include <hip/hip_runtime.h>
#include <hip/hip_bf16.h>
#include <stdint.h>

#define T_STEPS 256
#define B_SZ    256
#define NI      128
#define NR      512
#define NO      64
#define BT      16    // batch rows per group
#define NG      16    // groups
#define HALF_R  256   // output cols per WG (half of NR)

typedef __attribute__((ext_vector_type(8))) short short8;
typedef __attribute__((ext_vector_type(4))) short short4v;
typedef __attribute__((ext_vector_type(4))) float f32x4;

__device__ __forceinline__ unsigned short f2bf(float f) {
    union { float f; unsigned u; } v; v.f = f;
    unsigned u = v.u;
    return (unsigned short)((u + 0x7FFFu + ((u >> 16) & 1u)) >> 16);
}

// ---------------------------------------------------------------------------
// Persistent scan kernel: 32 blocks x 512 threads.
// block = (group = bid & 15, half = bid >> 4). Pair (g, g+16) -> same XCD
// under round-robin dispatch (speed heuristic only; correctness via
// device-scope fences + atomics).
// Each WG: batch rows [grp*16, +16), output cols [half*256, +256).
// Wrec/Wi halves live in registers as bf16 MFMA B-fragments.
// ---------------------------------------------------------------------------
__global__ __launch_bounds__(512) void rnn_scan(
    const float* __restrict__ inputs, const float* __restrict__ noise,
    const float* __restrict__ Wi, const float* __restrict__ bi,
    const float* __restrict__ Wrec,
    float* __restrict__ dout, unsigned short* __restrict__ Xbuf,
    int* __restrict__ flags)
{
    const int bid  = blockIdx.x;
    const int grp  = bid & 15;
    const int half = bid >> 4;
    const int b0   = grp * BT;
    const int tid  = threadIdx.x;
    const int w    = tid >> 6;       // wave 0..7
    const int l    = tid & 63;
    const int l15  = l & 15;
    const int l4   = l >> 4;

    // LDS: double-buffered H tile [16][512] bf16 (swizzled) + input tile [16][128] bf16
    __shared__ __align__(16) unsigned char Hl[2][BT * 1024];
    __shared__ __align__(16) unsigned char Il[2][BT * 256];

    // ---- load register-resident B fragments (bf16) ----
    short8 Bh[2][16];   // Wrec half: 2 col-tiles x 16 k-tiles
    short8 Bw[2][4];    // Wi half:   2 col-tiles x 4 k-tiles
    float  biv[2];
    #pragma unroll
    for (int ct = 0; ct < 2; ++ct) {
        const int n = half * HALF_R + w * 32 + ct * 16 + l15;
        biv[ct] = bi[n];
        #pragma unroll
        for (int kt = 0; kt < 16; ++kt) {
            const float* src = Wrec + (size_t)n * NR + kt * 32 + l4 * 8;
            short8 f;
            #pragma unroll
            for (int j = 0; j < 8; ++j) f[j] = (short)f2bf(src[j]);
            Bh[ct][kt] = f;
        }
        #pragma unroll
        for (int kt = 0; kt < 4; ++kt) {
            const float* src = Wi + (size_t)n * NI + kt * 32 + l4 * 8;
            short8 f;
            #pragma unroll
            for (int j = 0; j < 8; ++j) f[j] = (short)f2bf(src[j]);
            Bw[ct][kt] = f;
        }
    }

    // ---- stage inputs[0] into Il[0] ----
    {
        const int f = tid * 4, row = f >> 7, c = f & 127;
        const float4 v = *(const float4*)(inputs + ((size_t)(b0 + row)) * NI + c);
        short4v pk;
        pk[0] = (short)f2bf(v.x); pk[1] = (short)f2bf(v.y);
        pk[2] = (short)f2bf(v.z); pk[3] = (short)f2bf(v.w);
        const unsigned off = row * 256 + ((unsigned)(2 * c) ^ ((row & 7) << 4));
        *(short4v*)(&Il[0][off]) = pk;
    }
    __syncthreads();

    unsigned short* Xg = Xbuf + (size_t)grp * 2 * BT * NR;   // [parity][row][col]
    int* myflag = flags + (grp * 2 + half) * 64;
    int* pflag  = flags + (grp * 2 + (half ^ 1)) * 64;

    float* hout   = dout + (size_t)NO * B_SZ;
    float* hidout = dout + (size_t)NO * B_SZ + (size_t)T_STEPS * B_SZ * NR;

    const unsigned swzA = (unsigned)((l15 & 7) << 4);

    for (int t = 0; t < T_STEPS; ++t) {
        const int p = t & 1, pn = p ^ 1;
        f32x4 acc[2];
        acc[0] = (f32x4){0.f, 0.f, 0.f, 0.f};
        acc[1] = (f32x4){0.f, 0.f, 0.f, 0.f};

        // proj contribution: inputs[t] (16x128) x Wi^T
        #pragma unroll
        for (int kt = 0; kt < 4; ++kt) {
            const unsigned off = l15 * 256 + (((unsigned)(kt * 64 + l4 * 16)) ^ swzA);
            const short8 a = *(const short8*)(&Il[p][off]);
            acc[0] = __builtin_amdgcn_mfma_f32_16x16x32_bf16(a, Bw[0][kt], acc[0], 0, 0, 0);
            acc[1] = __builtin_amdgcn_mfma_f32_16x16x32_bf16(a, Bw[1][kt], acc[1], 0, 0, 0);
        }
        // recurrent contribution: H (16x512) x Wrec^T   (h0 == 0 -> skip at t=0)
        if (t > 0) {
            #pragma unroll
            for (int kt = 0; kt < 16; ++kt) {
                const unsigned off = l15 * 1024 + (((unsigned)(kt * 64 + l4 * 16)) ^ swzA);
                const short8 a = *(const short8*)(&Hl[p][off]);
                acc[0] = __builtin_amdgcn_mfma_f32_16x16x32_bf16(a, Bh[0][kt], acc[0], 0, 0, 0);
                acc[1] = __builtin_amdgcn_mfma_f32_16x16x32_bf16(a, Bh[1][kt], acc[1], 0, 0, 0);
            }
        }

        // epilogue: + bias + noise(t<4), relu, write h (f32) + exchange (bf16)
        #pragma unroll
        for (int ct = 0; ct < 2; ++ct) {
            const int n = half * HALF_R + w * 32 + ct * 16 + l15;
            #pragma unroll
            for (int q = 0; q < 4; ++q) {
                const int m = l4 * 4 + q;
                float v = acc[ct][q] + biv[ct];
                if (t < 4) v += noise[((size_t)t * B_SZ + b0 + m) * NR + n];
                v = v > 0.f ? v : 0.f;
                hout[((size_t)t * B_SZ + b0 + m) * NR + n] = v;
                if (t == T_STEPS - 1) {
                    hidout[(size_t)(b0 + m) * NR + n] = v;
                } else {
                    const unsigned short hb = f2bf(v);
                    const unsigned off = m * 1024 + ((unsigned)(2 * n) ^ ((m & 7) << 4));
                    *(unsigned short*)(&Hl[pn][off]) = hb;            // own half -> LDS
                    Xg[((size_t)pn * BT + m) * NR + n] = hb;          // own half -> global
                }
            }
        }
        if (t == T_STEPS - 1) break;

        __syncthreads();                       // all X writes issued & drained
        if (tid == 0) {
            __threadfence();                   // make them device-visible
            __hip_atomic_store(myflag, t + 1, __ATOMIC_RELEASE, __HIP_MEMORY_SCOPE_AGENT);
        }
        while (__hip_atomic_load(pflag, __ATOMIC_RELAXED, __HIP_MEMORY_SCOPE_AGENT) < t + 1) {}
        __threadfence();                       // acquire partner's writes

        // stage partner half of X[pn] -> Hl[pn]  (512 thr x 8 bf16 = 16x256)
        {
            const int e = tid * 8, row = e >> 8, kk = e & 255;
            const int kglob = (half ^ 1) * HALF_R + kk;
            const short8 v = *(const short8*)(Xg + ((size_t)pn * BT + row) * NR + kglob);
            const unsigned off = row * 1024 + ((unsigned)(2 * kglob) ^ ((row & 7) << 4));
            *(short8*)(&Hl[pn][off]) = v;
        }
        // stage inputs[t+1] -> Il[pn]
        {
            const int f = tid * 4, row = f >> 7, c = f & 127;
            const float4 v = *(const float4*)(inputs + ((size_t)(t + 1) * B_SZ + b0 + row) * NI + c);
            short4v pk;
            pk[0] = (short)f2bf(v.x); pk[1] = (short)f2bf(v.y);
            pk[2] = (short)f2bf(v.z); pk[3] = (short)f2bf(v.w);
            const unsigned off = row * 256 + ((unsigned)(2 * c) ^ ((row & 7) << 4));
            *(short4v*)(&Il[pn][off]) = pk;
        }
        __syncthreads();
    }
}

// ---------------------------------------------------------------------------
// Output head: softmax(hidden @ Wo^T + bo). 256 blocks (one batch row) x 256.
// ---------------------------------------------------------------------------
__global__ __launch_bounds__(256) void rnn_out(
    const float* __restrict__ Wo, const float* __restrict__ bo,
    float* __restrict__ dout)
{
    const float* hidden = dout + (size_t)NO * B_SZ + (size_t)T_STEPS * B_SZ * NR;
    const int b = blockIdx.x;
    const int tid = threadIdx.x, w = tid >> 6, l = tid & 63;

    __shared__ float hid[NR];
    __shared__ float lg[NO];

    if (tid < 128) {
        *(float4*)(&hid[tid * 4]) = *(const float4*)(hidden + (size_t)b * NR + tid * 4);
    }
    __syncthreads();

    #pragma unroll 1
    for (int jj = 0; jj < 16; ++jj) {
        const int j = w * 16 + jj;
        const float4* wr = (const float4*)(Wo + (size_t)j * NR + l * 8);
        const float4 a = wr[0], c = wr[1];
        const float4 h0 = *(const float4*)(&hid[l * 8]);
        const float4 h1 = *(const float4*)(&hid[l * 8 + 4]);
        float s = a.x * h0.x + a.y * h0.y + a.z * h0.z + a.w * h0.w
                + c.x * h1.x + c.y * h1.y + c.z * h1.z + c.w * h1.w;
        #pragma unroll
        for (int d = 32; d > 0; d >>= 1) s += __shfl_xor(s, d, 64);
        if (l == 0) lg[j] = s + bo[j];
    }
    __syncthreads();

    if (tid < 64) {
        const float x = lg[tid];
        float mx = x;
        #pragma unroll
        for (int d = 32; d > 0; d >>= 1) mx = fmaxf(mx, __shfl_xor(mx, d, 64));
        const float e = __expf(x - mx);
        float sum = e;
        #pragma unroll
        for (int d = 32; d > 0; d >>= 1) sum += __shfl_xor(sum, d, 64);
        dout[(size_t)b * NO + tid] = e / sum;
    }
}

extern "C" void kernel_launch(void* const* d_in, const int* in_sizes, int n_in,
                              void* d_out, int out_size, void* d_ws, size_t ws_size,
                              hipStream_t stream) {
    const float* inputs = (const float*)d_in[0];
    const float* noise  = (const float*)d_in[1];
    const float* Wi     = (const float*)d_in[2];
    const float* bi     = (const float*)d_in[3];
    const float* Wrec   = (const float*)d_in[4];
    const float* Wo     = (const float*)d_in[5];
    const float* bo     = (const float*)d_in[6];
    float* out = (float*)d_out;

    int* flags = (int*)d_ws;                                   // 32 flags x 256 B
    unsigned short* Xbuf = (unsigned short*)((char*)d_ws + 8192);  // 16 grp x 2 x 16 x 512 bf16

    hipMemsetAsync(d_ws, 0, 8192, stream);   // zero handshake flags each call
    rnn_scan<<<32, 512, 0, stream>>>(inputs, noise, Wi, bi, Wrec, out, Xbuf, flags);
    rnn_out<<<256, 256, 0, stream>>>(Wo, bo, out);
}

// Round 2
// 1794.228 us; speedup vs baseline: 1.0356x; 1.0356x over previous
//
#include <hip/hip_runtime.h>
#include <hip/hip_bf16.h>
#include <stdint.h>

#define T_STEPS 256
#define B_SZ    256
#define NI      128
#define NR      512
#define NO      64
#define BT      16    // batch rows per group
#define HALF_R  256   // output cols per WG (half of NR)

typedef __attribute__((ext_vector_type(8))) short short8;
typedef __attribute__((ext_vector_type(4))) short short4v;
typedef __attribute__((ext_vector_type(4))) float f32x4;
typedef __attribute__((ext_vector_type(2))) unsigned long long u64x2;

__device__ __forceinline__ unsigned short f2bf(float f) {
    union { float f; unsigned u; } v; v.f = f;
    unsigned u = v.u;
    return (unsigned short)((u + 0x7FFFu + ((u >> 16) & 1u)) >> 16);
}

// 8 recurrent K-tiles with compile-time K-tile base (keeps Bh[] indices static
// -> registers, not scratch).
template<int KTB>
__device__ __forceinline__ void recur8(const unsigned char* Hbuf,
                                       const short8 (&Bh)[2][16],
                                       f32x4& acc0, f32x4& acc1,
                                       int l15, int l4, unsigned swzA) {
    #pragma unroll
    for (int kk = 0; kk < 8; ++kk) {
        const unsigned off = l15 * 1024 + (((unsigned)((KTB + kk) * 64 + l4 * 16)) ^ swzA);
        const short8 a = *(const short8*)(Hbuf + off);
        acc0 = __builtin_amdgcn_mfma_f32_16x16x32_bf16(a, Bh[0][KTB + kk], acc0, 0, 0, 0);
        acc1 = __builtin_amdgcn_mfma_f32_16x16x32_bf16(a, Bh[1][KTB + kk], acc1, 0, 0, 0);
    }
}

// ---------------------------------------------------------------------------
// Persistent scan kernel: 32 blocks x 512 threads.
// block = (group = bid & 15, half = bid >> 4).
// Exchange of the 16x256 bf16 half-h per step goes through Infinity Cache via
// relaxed agent-scope atomics (cache-bypassing, NO threadfence / L2 flush).
// ---------------------------------------------------------------------------
__global__ __launch_bounds__(512) void rnn_scan(
    const float* __restrict__ inputs, const float* __restrict__ noise,
    const float* __restrict__ Wi, const float* __restrict__ bi,
    const float* __restrict__ Wrec,
    float* __restrict__ dout, unsigned* __restrict__ Xbuf,
    int* __restrict__ flags)
{
    const int bid  = blockIdx.x;
    const int grp  = bid & 15;
    const int half = bid >> 4;
    const int b0   = grp * BT;
    const int tid  = threadIdx.x;
    const int w    = tid >> 6;       // wave 0..7
    const int l    = tid & 63;
    const int l15  = l & 15;
    const int l4   = l >> 4;

    // LDS: double-buffered H tile [16][512] bf16 (swizzled) + input tile [16][128] bf16
    __shared__ __align__(16) unsigned char Hl[2][BT * 1024];
    __shared__ __align__(16) unsigned char Il[2][BT * 256];

    // ---- register-resident B fragments (bf16) ----
    short8 Bh[2][16];   // Wrec half: 2 col-tiles x 16 k-tiles
    short8 Bw[2][4];    // Wi half:   2 col-tiles x 4 k-tiles
    float  biv[2];
    #pragma unroll
    for (int ct = 0; ct < 2; ++ct) {
        const int n = half * HALF_R + w * 32 + ct * 16 + l15;
        biv[ct] = bi[n];
        #pragma unroll
        for (int kt = 0; kt < 16; ++kt) {
            const float* src = Wrec + (size_t)n * NR + kt * 32 + l4 * 8;
            short8 f;
            #pragma unroll
            for (int j = 0; j < 8; ++j) f[j] = (short)f2bf(src[j]);
            Bh[ct][kt] = f;
        }
        #pragma unroll
        for (int kt = 0; kt < 4; ++kt) {
            const float* src = Wi + (size_t)n * NI + kt * 32 + l4 * 8;
            short8 f;
            #pragma unroll
            for (int j = 0; j < 8; ++j) f[j] = (short)f2bf(src[j]);
            Bw[ct][kt] = f;
        }
    }

    // ---- stage inputs[0] into Il[0] ----
    {
        const int f = tid * 4, row = f >> 7, c = f & 127;
        const float4 v = *(const float4*)(inputs + ((size_t)(b0 + row)) * NI + c);
        short4v pk;
        pk[0] = (short)f2bf(v.x); pk[1] = (short)f2bf(v.y);
        pk[2] = (short)f2bf(v.z); pk[3] = (short)f2bf(v.w);
        const unsigned off = row * 256 + ((unsigned)(2 * c) ^ ((row & 7) << 4));
        *(short4v*)(&Il[0][off]) = pk;
    }
    __syncthreads();

    // exchange buffer: per group [parity][half][16 rows][128 u32 (=256 bf16)]
    unsigned* Xg = Xbuf + (size_t)grp * 8192;
    int* myflag = flags + (grp * 2 + half) * 64;
    int* pflag  = flags + (grp * 2 + (half ^ 1)) * 64;

    float* hout   = dout + (size_t)NO * B_SZ;
    float* hidout = hout + (size_t)T_STEPS * B_SZ * NR;

    const unsigned swzA = (unsigned)((l15 & 7) << 4);

    f32x4 acc0 = (f32x4){0.f, 0.f, 0.f, 0.f};
    f32x4 acc1 = (f32x4){0.f, 0.f, 0.f, 0.f};

    // prologue: proj(0)
    #pragma unroll
    for (int kt = 0; kt < 4; ++kt) {
        const unsigned off = l15 * 256 + (((unsigned)(kt * 64 + l4 * 16)) ^ swzA);
        const short8 a = *(const short8*)(&Il[0][off]);
        acc0 = __builtin_amdgcn_mfma_f32_16x16x32_bf16(a, Bw[0][kt], acc0, 0, 0, 0);
        acc1 = __builtin_amdgcn_mfma_f32_16x16x32_bf16(a, Bw[1][kt], acc1, 0, 0, 0);
    }
    // prologue: noise(0) prefetch
    float nz[2][4];
    #pragma unroll
    for (int ct = 0; ct < 2; ++ct) {
        const int n = half * HALF_R + w * 32 + ct * 16 + l15;
        #pragma unroll
        for (int q = 0; q < 4; ++q) {
            const int m = l4 * 4 + q;
            nz[ct][q] = noise[((size_t)0 * B_SZ + b0 + m) * NR + n];
        }
    }

    for (int t = 0; t < T_STEPS; ++t) {
        const int p = t & 1, pn = p ^ 1;

        // partner-half recurrent contribution (needs exchanged h[t-1])
        if (t > 0) {
            if (half == 0) recur8<8>(&Hl[p][0], Bh, acc0, acc1, l15, l4, swzA);
            else           recur8<0>(&Hl[p][0], Bh, acc0, acc1, l15, l4, swzA);
        }

        // epilogue: v = relu(acc + bias + noise)
        float vkeep[2][4];
        #pragma unroll
        for (int ct = 0; ct < 2; ++ct) {
            #pragma unroll
            for (int q = 0; q < 4; ++q) {
                float v = (ct == 0 ? acc0[q] : acc1[q]) + biv[ct] + nz[ct][q];
                vkeep[ct][q] = v > 0.f ? v : 0.f;
            }
        }

        if (t == T_STEPS - 1) {
            #pragma unroll
            for (int ct = 0; ct < 2; ++ct) {
                const int n = half * HALF_R + w * 32 + ct * 16 + l15;
                #pragma unroll
                for (int q = 0; q < 4; ++q) {
                    const int m = l4 * 4 + q;
                    hout[((size_t)t * B_SZ + b0 + m) * NR + n] = vkeep[ct][q];
                    hidout[(size_t)(b0 + m) * NR + n] = vkeep[ct][q];
                }
            }
            break;
        }

        // own half: packed u32 -> LDS Hl[pn] + IF exchange buffer (even lanes)
        #pragma unroll
        for (int ct = 0; ct < 2; ++ct) {
            #pragma unroll
            for (int q = 0; q < 4; ++q) {
                const int m = l4 * 4 + q;
                const float other = __shfl_xor(vkeep[ct][q], 1, 64);
                if (!(l & 1)) {
                    const int nloc  = w * 32 + ct * 16 + l15;        // even
                    const int nglob = half * HALF_R + nloc;
                    const unsigned pk = (unsigned)f2bf(vkeep[ct][q]) |
                                        ((unsigned)f2bf(other) << 16);
                    const unsigned off = m * 1024 +
                        (((unsigned)(2 * nglob)) ^ ((unsigned)((m & 7) << 4)));
                    *(unsigned*)(&Hl[pn][off]) = pk;
                    __hip_atomic_store(Xg + ((pn * 2 + half) * 16 + m) * 128 + (nloc >> 1),
                                       pk, __ATOMIC_RELAXED, __HIP_MEMORY_SCOPE_AGENT);
                }
            }
        }

        // stage inputs[t+1] -> Il[pn]
        {
            const int f = tid * 4, row = f >> 7, c = f & 127;
            const float4 v = *(const float4*)(inputs + ((size_t)(t + 1) * B_SZ + b0 + row) * NI + c);
            short4v pk;
            pk[0] = (short)f2bf(v.x); pk[1] = (short)f2bf(v.y);
            pk[2] = (short)f2bf(v.z); pk[3] = (short)f2bf(v.w);
            const unsigned off = row * 256 + ((unsigned)(2 * c) ^ ((row & 7) << 4));
            *(short4v*)(&Il[pn][off]) = pk;
        }

        asm volatile("s_waitcnt vmcnt(0)" ::: "memory"); // exports at coherence point
        __syncthreads();                                 // (all threads drained)
        if (tid == 0)
            __hip_atomic_store(myflag, t + 1, __ATOMIC_RELAXED, __HIP_MEMORY_SCOPE_AGENT);

        // ---- overlap window: everything not needing partner's h[t] ----
        // h[t] f32 store (fire and forget)
        #pragma unroll
        for (int ct = 0; ct < 2; ++ct) {
            const int n = half * HALF_R + w * 32 + ct * 16 + l15;
            #pragma unroll
            for (int q = 0; q < 4; ++q) {
                const int m = l4 * 4 + q;
                hout[((size_t)t * B_SZ + b0 + m) * NR + n] = vkeep[ct][q];
            }
        }
        // proj(t+1)
        acc0 = (f32x4){0.f, 0.f, 0.f, 0.f};
        acc1 = (f32x4){0.f, 0.f, 0.f, 0.f};
        #pragma unroll
        for (int kt = 0; kt < 4; ++kt) {
            const unsigned off = l15 * 256 + (((unsigned)(kt * 64 + l4 * 16)) ^ swzA);
            const short8 a = *(const short8*)(&Il[pn][off]);
            acc0 = __builtin_amdgcn_mfma_f32_16x16x32_bf16(a, Bw[0][kt], acc0, 0, 0, 0);
            acc1 = __builtin_amdgcn_mfma_f32_16x16x32_bf16(a, Bw[1][kt], acc1, 0, 0, 0);
        }
        // own-half recurrent(t+1): own h[t] already in Hl[pn]
        if (half == 0) recur8<0>(&Hl[pn][0], Bh, acc0, acc1, l15, l4, swzA);
        else           recur8<8>(&Hl[pn][0], Bh, acc0, acc1, l15, l4, swzA);
        // noise(t+1) prefetch
        if (t + 1 < 4) {
            #pragma unroll
            for (int ct = 0; ct < 2; ++ct) {
                const int n = half * HALF_R + w * 32 + ct * 16 + l15;
                #pragma unroll
                for (int q = 0; q < 4; ++q) {
                    const int m = l4 * 4 + q;
                    nz[ct][q] = noise[((size_t)(t + 1) * B_SZ + b0 + m) * NR + n];
                }
            }
        } else {
            #pragma unroll
            for (int ct = 0; ct < 2; ++ct)
                #pragma unroll
                for (int q = 0; q < 4; ++q) nz[ct][q] = 0.f;
        }

        // ---- wait for partner's h[t] half, pull from IF, place in LDS ----
        while (__hip_atomic_load(pflag, __ATOMIC_RELAXED, __HIP_MEMORY_SCOPE_AGENT) < t + 1) {}
        {
            const int row = tid >> 5;
            const int c4  = (tid & 31) * 4;   // u32 column
            const unsigned* src = Xg + ((pn * 2 + (half ^ 1)) * 16 + row) * 128 + c4;
            const unsigned long long d0 =
                __hip_atomic_load((const unsigned long long*)src,     __ATOMIC_RELAXED, __HIP_MEMORY_SCOPE_AGENT);
            const unsigned long long d1 =
                __hip_atomic_load((const unsigned long long*)(src + 2), __ATOMIC_RELAXED, __HIP_MEMORY_SCOPE_AGENT);
            u64x2 dd; dd[0] = d0; dd[1] = d1;
            const unsigned off = row * 1024 +
                (((unsigned)((half ^ 1) * 512 + (tid & 31) * 16)) ^ ((unsigned)((row & 7) << 4)));
            *(u64x2*)(&Hl[pn][off]) = dd;
        }
        __syncthreads();
    }
}

// ---------------------------------------------------------------------------
// Output head: softmax(hidden @ Wo^T + bo). 256 blocks (one batch row) x 256.
// ---------------------------------------------------------------------------
__global__ __launch_bounds__(256) void rnn_out(
    const float* __restrict__ Wo, const float* __restrict__ bo,
    float* __restrict__ dout)
{
    const float* hidden = dout + (size_t)NO * B_SZ + (size_t)T_STEPS * B_SZ * NR;
    const int b = blockIdx.x;
    const int tid = threadIdx.x, w = tid >> 6, l = tid & 63;

    __shared__ float hid[NR];
    __shared__ float lg[NO];

    if (tid < 128) {
        *(float4*)(&hid[tid * 4]) = *(const float4*)(hidden + (size_t)b * NR + tid * 4);
    }
    __syncthreads();

    #pragma unroll 1
    for (int jj = 0; jj < 16; ++jj) {
        const int j = w * 16 + jj;
        const float4* wr = (const float4*)(Wo + (size_t)j * NR + l * 8);
        const float4 a = wr[0], c = wr[1];
        const float4 h0 = *(const float4*)(&hid[l * 8]);
        const float4 h1 = *(const float4*)(&hid[l * 8 + 4]);
        float s = a.x * h0.x + a.y * h0.y + a.z * h0.z + a.w * h0.w
                + c.x * h1.x + c.y * h1.y + c.z * h1.z + c.w * h1.w;
        #pragma unroll
        for (int d = 32; d > 0; d >>= 1) s += __shfl_xor(s, d, 64);
        if (l == 0) lg[j] = s + bo[j];
    }
    __syncthreads();

    if (tid < 64) {
        const float x = lg[tid];
        float mx = x;
        #pragma unroll
        for (int d = 32; d > 0; d >>= 1) mx = fmaxf(mx, __shfl_xor(mx, d, 64));
        const float e = __expf(x - mx);
        float sum = e;
        #pragma unroll
        for (int d = 32; d > 0; d >>= 1) sum += __shfl_xor(sum, d, 64);
        dout[(size_t)b * NO + tid] = e / sum;
    }
}

extern "C" void kernel_launch(void* const* d_in, const int* in_sizes, int n_in,
                              void* d_out, int out_size, void* d_ws, size_t ws_size,
                              hipStream_t stream) {
    const float* inputs = (const float*)d_in[0];
    const float* noise  = (const float*)d_in[1];
    const float* Wi     = (const float*)d_in[2];
    const float* bi     = (const float*)d_in[3];
    const float* Wrec   = (const float*)d_in[4];
    const float* Wo     = (const float*)d_in[5];
    const float* bo     = (const float*)d_in[6];
    float* out = (float*)d_out;

    int* flags = (int*)d_ws;                                  // 32 flags x 256 B
    unsigned* Xbuf = (unsigned*)((char*)d_ws + 8192);         // 16 grp x 32 KB

    hipMemsetAsync(d_ws, 0, 8192, stream);   // zero handshake flags each call
    rnn_scan<<<32, 512, 0, stream>>>(inputs, noise, Wi, bi, Wrec, out, Xbuf, flags);
    rnn_out<<<256, 256, 0, stream>>>(Wo, bo, out);
}

// Round 3
// 722.611 us; speedup vs baseline: 2.5714x; 2.4830x over previous
//
#include <hip/hip_runtime.h>
#include <hip/hip_bf16.h>
#include <stdint.h>

#define T_STEPS 256
#define B_SZ    256
#define NI      128
#define NR      512
#define NO      64
#define BT      16    // batch rows per group
#define HALF_R  256   // output cols per WG (half of NR)

typedef __attribute__((ext_vector_type(8))) short short8;
typedef __attribute__((ext_vector_type(4))) short short4v;
typedef __attribute__((ext_vector_type(4))) float f32x4;
typedef __attribute__((ext_vector_type(2))) unsigned long long u64x2;

__device__ __forceinline__ unsigned short f2bf(float f) {
    union { float f; unsigned u; } v; v.f = f;
    unsigned u = v.u;
    return (unsigned short)((u + 0x7FFFu + ((u >> 16) & 1u)) >> 16);
}

// 8 recurrent K-tiles with compile-time K-tile base (static Bh[] indices).
template<int KTB>
__device__ __forceinline__ void recur8(const unsigned char* Hbuf,
                                       const short8 (&Bh)[2][16],
                                       f32x4& acc0, f32x4& acc1,
                                       int l15, int l4, unsigned swzA) {
    #pragma unroll
    for (int kk = 0; kk < 8; ++kk) {
        const unsigned off = l15 * 1024 + (((unsigned)((KTB + kk) * 64 + l4 * 16)) ^ swzA);
        const short8 a = *(const short8*)(Hbuf + off);
        acc0 = __builtin_amdgcn_mfma_f32_16x16x32_bf16(a, Bh[0][KTB + kk], acc0, 0, 0, 0);
        acc1 = __builtin_amdgcn_mfma_f32_16x16x32_bf16(a, Bh[1][KTB + kk], acc1, 0, 0, 0);
    }
}

// ---------------------------------------------------------------------------
// proj GEMM: proj[t*B+b][n] = (bf16(inputs[t,b,:]) @ bf16(Wi)^T)[n] + bi[n]
//            + (t<4 ? noise[t,b,n] : 0).   M=65536, N=512, K=128.
// Block 256 thr (4 waves), tile 64 rows x 128 cols. Grid (1024, 4).
// ---------------------------------------------------------------------------
__global__ __launch_bounds__(256) void proj_gemm(
    const float* __restrict__ inputs, const float* __restrict__ Wi,
    const float* __restrict__ bi, const float* __restrict__ noise,
    float* __restrict__ proj)
{
    const int mb = blockIdx.x;
    const int nb = blockIdx.y;
    const int m0 = mb * 64, n0 = nb * 128;
    const int tid = threadIdx.x, w = tid >> 6, l = tid & 63;
    const int l15 = l & 15, l4 = l >> 4;

    __shared__ __align__(16) unsigned char Al[64 * 256];    // 16 KB bf16 swizzled
    __shared__ __align__(16) unsigned char Wl[128 * 256];   // 32 KB bf16 swizzled

    #pragma unroll
    for (int j = 0; j < 8; ++j) {
        const int f = j * 256 + tid;
        const int row = f >> 5, c4 = f & 31;
        const float4 v = *(const float4*)(inputs + (size_t)(m0 + row) * NI + c4 * 4);
        short4v pk;
        pk[0] = (short)f2bf(v.x); pk[1] = (short)f2bf(v.y);
        pk[2] = (short)f2bf(v.z); pk[3] = (short)f2bf(v.w);
        *(short4v*)(&Al[row * 256 + (((unsigned)(c4 * 8)) ^ ((row & 7) << 4))]) = pk;
    }
    #pragma unroll
    for (int j = 0; j < 16; ++j) {
        const int f = j * 256 + tid;
        const int r = f >> 5, c4 = f & 31;
        const float4 v = *(const float4*)(Wi + (size_t)(n0 + r) * NI + c4 * 4);
        short4v pk;
        pk[0] = (short)f2bf(v.x); pk[1] = (short)f2bf(v.y);
        pk[2] = (short)f2bf(v.z); pk[3] = (short)f2bf(v.w);
        *(short4v*)(&Wl[r * 256 + (((unsigned)(c4 * 8)) ^ ((r & 7) << 4))]) = pk;
    }
    __syncthreads();

    f32x4 acc[8];
    #pragma unroll
    for (int nt = 0; nt < 8; ++nt) acc[nt] = (f32x4){0.f, 0.f, 0.f, 0.f};
    #pragma unroll
    for (int kt = 0; kt < 4; ++kt) {
        const short8 a = *(const short8*)(
            &Al[(w * 16 + l15) * 256 + (((unsigned)(kt * 64 + l4 * 16)) ^ ((l15 & 7) << 4))]);
        #pragma unroll
        for (int nt = 0; nt < 8; ++nt) {
            const short8 b = *(const short8*)(
                &Wl[(nt * 16 + l15) * 256 + (((unsigned)(kt * 64 + l4 * 16)) ^ ((l15 & 7) << 4))]);
            acc[nt] = __builtin_amdgcn_mfma_f32_16x16x32_bf16(a, b, acc[nt], 0, 0, 0);
        }
    }

    const int t = m0 >> 8;   // 64-row tiles never cross a t boundary (256/64)
    #pragma unroll
    for (int nt = 0; nt < 8; ++nt) {
        const int n = n0 + nt * 16 + l15;
        const float bv = bi[n];
        #pragma unroll
        for (int q = 0; q < 4; ++q) {
            const int gr = m0 + w * 16 + l4 * 4 + q;
            float v = acc[nt][q] + bv;
            if (t < 4) v += noise[(size_t)gr * NR + n];
            proj[(size_t)gr * NR + n] = v;
        }
    }
}

// ---------------------------------------------------------------------------
// Persistent scan: 32 blocks x 512 threads; block = (grp = bid&15, half = bid>>4).
// h[t] = relu(proj[t] + h[t-1] @ Wrec^T); Wrec half register-resident (bf16).
// Cross-block half-h exchange via IF-coherent (sc0 sc1) relaxed atomics;
// per-wave drain + counter flag; raw s_barrier with lgkmcnt-only waits.
// ---------------------------------------------------------------------------
__global__ __launch_bounds__(512) void rnn_scan(
    const float* __restrict__ Wrec,
    float* __restrict__ dout,
    unsigned* __restrict__ Xbuf,
    int* __restrict__ flags)
{
    const int bid  = blockIdx.x;
    const int grp  = bid & 15;
    const int half = bid >> 4;
    const int b0   = grp * BT;
    const int tid  = threadIdx.x;
    const int w    = tid >> 6;
    const int l    = tid & 63;
    const int l15  = l & 15;
    const int l4   = l >> 4;

    __shared__ __align__(16) unsigned char Hl[2][BT * 1024];  // 32 KB, swizzled bf16

    // Wrec half -> register fragments
    short8 Bh[2][16];
    #pragma unroll
    for (int ct = 0; ct < 2; ++ct) {
        const int n = half * HALF_R + w * 32 + ct * 16 + l15;
        #pragma unroll
        for (int kt = 0; kt < 16; ++kt) {
            const float* src = Wrec + (size_t)n * NR + kt * 32 + l4 * 8;
            short8 f;
            #pragma unroll
            for (int j = 0; j < 8; ++j) f[j] = (short)f2bf(src[j]);
            Bh[ct][kt] = f;
        }
    }

    unsigned* Xg = Xbuf + (size_t)grp * 8192;     // [parity][half][32 c][16 r][4 u32]
    int* myflag = flags + (grp * 2 + half) * 64;
    int* pflag  = flags + (grp * 2 + (half ^ 1)) * 64;

    float* hbuf   = dout + (size_t)NO * B_SZ;                 // proj in / h out
    float* hidout = hbuf + (size_t)T_STEPS * B_SZ * NR;

    const unsigned swzA = (unsigned)((l15 & 7) << 4);
    const int n0 = half * HALF_R + w * 32 + l15;   // ct=0 column
    const int n1 = n0 + 16;                        // ct=1 column
    const int mrow = l4 * 4;

    // prologue: acc = proj[0]
    f32x4 acc0, acc1;
    #pragma unroll
    for (int q = 0; q < 4; ++q) {
        acc0[q] = hbuf[(size_t)(b0 + mrow + q) * NR + n0];
        acc1[q] = hbuf[(size_t)(b0 + mrow + q) * NR + n1];
    }

    float pj0[4], pj1[4];

    for (int t = 0; t < T_STEPS; ++t) {
        const int pn = (t & 1) ^ 1;

        // phase A: partner-half recurrent contribution (needs exchanged h[t-1])
        if (t > 0) {
            if (half == 0) recur8<8>(&Hl[t & 1][0], Bh, acc0, acc1, l15, l4, swzA);
            else           recur8<0>(&Hl[t & 1][0], Bh, acc0, acc1, l15, l4, swzA);
        }

        float v0[4], v1[4];
        #pragma unroll
        for (int q = 0; q < 4; ++q) {
            v0[q] = fmaxf(acc0[q], 0.f);
            v1[q] = fmaxf(acc1[q], 0.f);
        }

        if (t == T_STEPS - 1) {
            #pragma unroll
            for (int q = 0; q < 4; ++q) {
                hbuf[((size_t)t * B_SZ + b0 + mrow + q) * NR + n0] = v0[q];
                hbuf[((size_t)t * B_SZ + b0 + mrow + q) * NR + n1] = v1[q];
                hidout[(size_t)(b0 + mrow + q) * NR + n0] = v0[q];
                hidout[(size_t)(b0 + mrow + q) * NR + n1] = v1[q];
            }
            break;
        }

        // phase B: pack pairs -> LDS own half + IF export (even lanes)
        unsigned* Xreg = Xg + (pn * 2 + half) * 2048;
        #pragma unroll
        for (int ct = 0; ct < 2; ++ct) {
            #pragma unroll
            for (int q = 0; q < 4; ++q) {
                const float v = ct ? v1[q] : v0[q];
                const float other = __shfl_xor(v, 1, 64);
                if (!(l & 1)) {
                    const int m = mrow + q;
                    const int nloc = w * 32 + ct * 16 + l15;      // even
                    const int nglob = half * HALF_R + nloc;
                    const unsigned pk = (unsigned)f2bf(v) | ((unsigned)f2bf(other) << 16);
                    const unsigned off = m * 1024 +
                        (((unsigned)(2 * nglob)) ^ ((unsigned)((m & 7) << 4)));
                    *(unsigned*)(&Hl[pn][off]) = pk;
                    const int j = nloc >> 1;
                    __hip_atomic_store(Xreg + (j >> 2) * 64 + m * 4 + (j & 3), pk,
                                       __ATOMIC_RELAXED, __HIP_MEMORY_SCOPE_AGENT);
                }
            }
        }
        // per-wave drain of exports, then counter bump (8 waves -> +8/step)
        asm volatile("s_waitcnt vmcnt(0)" ::: "memory");
        if (l == 0)
            __hip_atomic_fetch_add(myflag, 1, __ATOMIC_RELAXED, __HIP_MEMORY_SCOPE_AGENT);

        // barrier1: own-half pk visible in LDS (lgkm only; vmem stays in flight)
        asm volatile("s_waitcnt lgkmcnt(0)" ::: "memory");
        __builtin_amdgcn_sched_barrier(0);
        __builtin_amdgcn_s_barrier();
        __builtin_amdgcn_sched_barrier(0);

        // phase D: proj[t+1] prefetch, h[t] store, own-half recurrent for t+1
        #pragma unroll
        for (int q = 0; q < 4; ++q) {
            pj0[q] = hbuf[((size_t)(t + 1) * B_SZ + b0 + mrow + q) * NR + n0];
            pj1[q] = hbuf[((size_t)(t + 1) * B_SZ + b0 + mrow + q) * NR + n1];
        }
        #pragma unroll
        for (int q = 0; q < 4; ++q) {
            hbuf[((size_t)t * B_SZ + b0 + mrow + q) * NR + n0] = v0[q];
            hbuf[((size_t)t * B_SZ + b0 + mrow + q) * NR + n1] = v1[q];
        }
        acc0 = (f32x4){0.f, 0.f, 0.f, 0.f};
        acc1 = (f32x4){0.f, 0.f, 0.f, 0.f};
        if (half == 0) recur8<0>(&Hl[pn][0], Bh, acc0, acc1, l15, l4, swzA);
        else           recur8<8>(&Hl[pn][0], Bh, acc0, acc1, l15, l4, swzA);

        // phase E: wait for partner, pull its half from IF, add proj
        const int target = 8 * (t + 1);
        int fv;
        while ((fv = __hip_atomic_load(pflag, __ATOMIC_RELAXED,
                                       __HIP_MEMORY_SCOPE_AGENT)) < target) {}
        asm volatile("" :: "v"(fv) : "memory");   // pin pulls after poll
        {
            const int c = tid >> 4, r = tid & 15;
            const unsigned* src = Xg + (pn * 2 + (half ^ 1)) * 2048 + c * 64 + r * 4;
            const unsigned long long d0 = __hip_atomic_load(
                (const unsigned long long*)src, __ATOMIC_RELAXED, __HIP_MEMORY_SCOPE_AGENT);
            const unsigned long long d1 = __hip_atomic_load(
                (const unsigned long long*)(src + 2), __ATOMIC_RELAXED, __HIP_MEMORY_SCOPE_AGENT);
            u64x2 dd; dd[0] = d0; dd[1] = d1;
            const unsigned off = r * 1024 +
                (((unsigned)((half ^ 1) * 512 + c * 16)) ^ ((unsigned)((r & 7) << 4)));
            *(u64x2*)(&Hl[pn][off]) = dd;
        }
        #pragma unroll
        for (int q = 0; q < 4; ++q) { acc0[q] += pj0[q]; acc1[q] += pj1[q]; }

        // barrier2: pulled partner half visible in LDS
        asm volatile("s_waitcnt lgkmcnt(0)" ::: "memory");
        __builtin_amdgcn_sched_barrier(0);
        __builtin_amdgcn_s_barrier();
        __builtin_amdgcn_sched_barrier(0);
    }
}

// ---------------------------------------------------------------------------
// Output head: softmax(hidden @ Wo^T + bo). 256 blocks (one batch row) x 256.
// ---------------------------------------------------------------------------
__global__ __launch_bounds__(256) void rnn_out(
    const float* __restrict__ Wo, const float* __restrict__ bo,
    float* __restrict__ dout)
{
    const float* hidden = dout + (size_t)NO * B_SZ + (size_t)T_STEPS * B_SZ * NR;
    const int b = blockIdx.x;
    const int tid = threadIdx.x, w = tid >> 6, l = tid & 63;

    __shared__ float hid[NR];
    __shared__ float lg[NO];

    if (tid < 128) {
        *(float4*)(&hid[tid * 4]) = *(const float4*)(hidden + (size_t)b * NR + tid * 4);
    }
    __syncthreads();

    #pragma unroll 1
    for (int jj = 0; jj < 16; ++jj) {
        const int j = w * 16 + jj;
        const float4* wr = (const float4*)(Wo + (size_t)j * NR + l * 8);
        const float4 a = wr[0], c = wr[1];
        const float4 h0 = *(const float4*)(&hid[l * 8]);
        const float4 h1 = *(const float4*)(&hid[l * 8 + 4]);
        float s = a.x * h0.x + a.y * h0.y + a.z * h0.z + a.w * h0.w
                + c.x * h1.x + c.y * h1.y + c.z * h1.z + c.w * h1.w;
        #pragma unroll
        for (int d = 32; d > 0; d >>= 1) s += __shfl_xor(s, d, 64);
        if (l == 0) lg[j] = s + bo[j];
    }
    __syncthreads();

    if (tid < 64) {
        const float x = lg[tid];
        float mx = x;
        #pragma unroll
        for (int d = 32; d > 0; d >>= 1) mx = fmaxf(mx, __shfl_xor(mx, d, 64));
        const float e = __expf(x - mx);
        float sum = e;
        #pragma unroll
        for (int d = 32; d > 0; d >>= 1) sum += __shfl_xor(sum, d, 64);
        dout[(size_t)b * NO + tid] = e / sum;
    }
}

extern "C" void kernel_launch(void* const* d_in, const int* in_sizes, int n_in,
                              void* d_out, int out_size, void* d_ws, size_t ws_size,
                              hipStream_t stream) {
    const float* inputs = (const float*)d_in[0];
    const float* noise  = (const float*)d_in[1];
    const float* Wi     = (const float*)d_in[2];
    const float* bi     = (const float*)d_in[3];
    const float* Wrec   = (const float*)d_in[4];
    const float* Wo     = (const float*)d_in[5];
    const float* bo     = (const float*)d_in[6];
    float* out = (float*)d_out;

    int* flags = (int*)d_ws;                               // 32 counters x 256 B
    unsigned* Xbuf = (unsigned*)((char*)d_ws + 8192);      // 16 grp x 32 KB

    float* proj = out + (size_t)NO * B_SZ;   // proj lives in the h-output region

    hipMemsetAsync(d_ws, 0, 8192, stream);   // zero handshake counters each call
    proj_gemm<<<dim3(1024, 4), 256, 0, stream>>>(inputs, Wi, bi, noise, proj);
    rnn_scan<<<32, 512, 0, stream>>>(Wrec, out, Xbuf, flags);
    rnn_out<<<256, 256, 0, stream>>>(Wo, bo, out);
}

// Round 4
// 683.635 us; speedup vs baseline: 2.7180x; 1.0570x over previous
//
#include <hip/hip_runtime.h>
#include <hip/hip_bf16.h>
#include <stdint.h>

#define T_STEPS 256
#define B_SZ    256
#define NI      128
#define NR      512
#define NO      64
#define BT      16    // batch rows per group
#define HALF_R  256   // output cols per WG (half of NR)

typedef __attribute__((ext_vector_type(8))) short short8;
typedef __attribute__((ext_vector_type(4))) short short4v;
typedef __attribute__((ext_vector_type(4))) float f32x4;
typedef __attribute__((ext_vector_type(2))) unsigned long long u64x2;

__device__ __forceinline__ unsigned short f2bf(float f) {
    union { float f; unsigned u; } v; v.f = f;
    unsigned u = v.u;
    return (unsigned short)((u + 0x7FFFu + ((u >> 16) & 1u)) >> 16);
}

// 8 recurrent K-tiles with compile-time K-tile base (static Bh[] indices).
template<int KTB>
__device__ __forceinline__ void recur8(const unsigned char* Hbuf,
                                       const short8 (&Bh)[2][16],
                                       f32x4& acc0, f32x4& acc1,
                                       int l15, int l4, unsigned swzA) {
    #pragma unroll
    for (int kk = 0; kk < 8; ++kk) {
        const unsigned off = l15 * 1024 + (((unsigned)((KTB + kk) * 64 + l4 * 16)) ^ swzA);
        const short8 a = *(const short8*)(Hbuf + off);
        acc0 = __builtin_amdgcn_mfma_f32_16x16x32_bf16(a, Bh[0][KTB + kk], acc0, 0, 0, 0);
        acc1 = __builtin_amdgcn_mfma_f32_16x16x32_bf16(a, Bh[1][KTB + kk], acc1, 0, 0, 0);
    }
}

// ---------------------------------------------------------------------------
// proj GEMM: proj[t*B+b][n] = (bf16(inputs[t,b,:]) @ bf16(Wi)^T)[n] + bi[n]
//            + (t<4 ? noise[t,b,n] : 0).   M=65536, N=512, K=128.
// ---------------------------------------------------------------------------
__global__ __launch_bounds__(256) void proj_gemm(
    const float* __restrict__ inputs, const float* __restrict__ Wi,
    const float* __restrict__ bi, const float* __restrict__ noise,
    float* __restrict__ proj)
{
    const int mb = blockIdx.x;
    const int nb = blockIdx.y;
    const int m0 = mb * 64, n0 = nb * 128;
    const int tid = threadIdx.x, w = tid >> 6, l = tid & 63;
    const int l15 = l & 15, l4 = l >> 4;

    __shared__ __align__(16) unsigned char Al[64 * 256];    // 16 KB bf16 swizzled
    __shared__ __align__(16) unsigned char Wl[128 * 256];   // 32 KB bf16 swizzled

    #pragma unroll
    for (int j = 0; j < 8; ++j) {
        const int f = j * 256 + tid;
        const int row = f >> 5, c4 = f & 31;
        const float4 v = *(const float4*)(inputs + (size_t)(m0 + row) * NI + c4 * 4);
        short4v pk;
        pk[0] = (short)f2bf(v.x); pk[1] = (short)f2bf(v.y);
        pk[2] = (short)f2bf(v.z); pk[3] = (short)f2bf(v.w);
        *(short4v*)(&Al[row * 256 + (((unsigned)(c4 * 8)) ^ ((row & 7) << 4))]) = pk;
    }
    #pragma unroll
    for (int j = 0; j < 16; ++j) {
        const int f = j * 256 + tid;
        const int r = f >> 5, c4 = f & 31;
        const float4 v = *(const float4*)(Wi + (size_t)(n0 + r) * NI + c4 * 4);
        short4v pk;
        pk[0] = (short)f2bf(v.x); pk[1] = (short)f2bf(v.y);
        pk[2] = (short)f2bf(v.z); pk[3] = (short)f2bf(v.w);
        *(short4v*)(&Wl[r * 256 + (((unsigned)(c4 * 8)) ^ ((r & 7) << 4))]) = pk;
    }
    __syncthreads();

    f32x4 acc[8];
    #pragma unroll
    for (int nt = 0; nt < 8; ++nt) acc[nt] = (f32x4){0.f, 0.f, 0.f, 0.f};
    #pragma unroll
    for (int kt = 0; kt < 4; ++kt) {
        const short8 a = *(const short8*)(
            &Al[(w * 16 + l15) * 256 + (((unsigned)(kt * 64 + l4 * 16)) ^ ((l15 & 7) << 4))]);
        #pragma unroll
        for (int nt = 0; nt < 8; ++nt) {
            const short8 b = *(const short8*)(
                &Wl[(nt * 16 + l15) * 256 + (((unsigned)(kt * 64 + l4 * 16)) ^ ((l15 & 7) << 4))]);
            acc[nt] = __builtin_amdgcn_mfma_f32_16x16x32_bf16(a, b, acc[nt], 0, 0, 0);
        }
    }

    const int t = m0 >> 8;   // 64-row tiles never cross a t boundary
    #pragma unroll
    for (int nt = 0; nt < 8; ++nt) {
        const int n = n0 + nt * 16 + l15;
        const float bv = bi[n];
        #pragma unroll
        for (int q = 0; q < 4; ++q) {
            const int gr = m0 + w * 16 + l4 * 4 + q;
            float v = acc[nt][q] + bv;
            if (t < 4) v += noise[(size_t)gr * NR + n];
            proj[(size_t)gr * NR + n] = v;
        }
    }
}

// ---------------------------------------------------------------------------
// Persistent scan: 32 blocks x 512 threads; block = (grp = bid&15, half = bid>>4).
// h[t] = relu(proj[t] + h[t-1] @ Wrec^T); Wrec half register-resident (bf16).
// Cross-block exchange: SELF-FLAGGING tagged 8B atomics through IF. relu => all
// bf16 sign bits are 0; producer ORs a step-parity tag into the sign bits.
// Consumer polls the data lines directly (poll == pull). No fences, no flags,
// no export drains.
// ---------------------------------------------------------------------------
__global__ __launch_bounds__(512) void rnn_scan(
    const float* __restrict__ Wrec,
    float* __restrict__ dout,
    unsigned long long* __restrict__ Xbuf)
{
    const int bid  = blockIdx.x;
    const int grp  = bid & 15;
    const int half = bid >> 4;
    const int b0   = grp * BT;
    const int tid  = threadIdx.x;
    const int w    = tid >> 6;
    const int l    = tid & 63;
    const int l15  = l & 15;
    const int l4   = l >> 4;

    __shared__ __align__(16) unsigned char Hl[2][BT * 1024];  // 32 KB, swizzled bf16

    // Wrec half -> register fragments
    short8 Bh[2][16];
    #pragma unroll
    for (int ct = 0; ct < 2; ++ct) {
        const int n = half * HALF_R + w * 32 + ct * 16 + l15;
        #pragma unroll
        for (int kt = 0; kt < 16; ++kt) {
            const float* src = Wrec + (size_t)n * NR + kt * 32 + l4 * 8;
            short8 f;
            #pragma unroll
            for (int j = 0; j < 8; ++j) f[j] = (short)f2bf(src[j]);
            Bh[ct][kt] = f;
        }
    }

    // exchange: per (grp, parity, half): 16 rows x 64 u64 (= 256 bf16 cols)
    unsigned long long* Xg = Xbuf + (size_t)grp * 4096;

    float* hbuf   = dout + (size_t)NO * B_SZ;                 // proj in / h out
    float* hidout = hbuf + (size_t)T_STEPS * B_SZ * NR;

    const unsigned swzA = (unsigned)((l15 & 7) << 4);
    const int n0 = half * HALF_R + w * 32 + l15;   // ct=0 column
    const int n1 = n0 + 16;                        // ct=1 column
    const int mrow = l4 * 4;

    // prologue: acc = proj[0]
    f32x4 acc0, acc1;
    #pragma unroll
    for (int q = 0; q < 4; ++q) {
        acc0[q] = hbuf[(size_t)(b0 + mrow + q) * NR + n0];
        acc1[q] = hbuf[(size_t)(b0 + mrow + q) * NR + n1];
    }

    float pj0[4], pj1[4];

    for (int t = 0; t < T_STEPS; ++t) {
        const int pn = (t & 1) ^ 1;
        const int tag = ((t >> 1) & 1) ^ 1;   // parity-buffer reuse tag (1 first)

        // phase A: partner-half recurrent contribution (exchanged h[t-1])
        if (t > 0) {
            if (half == 0) recur8<8>(&Hl[t & 1][0], Bh, acc0, acc1, l15, l4, swzA);
            else           recur8<0>(&Hl[t & 1][0], Bh, acc0, acc1, l15, l4, swzA);
        }

        float v0[4], v1[4];
        #pragma unroll
        for (int q = 0; q < 4; ++q) {
            v0[q] = fmaxf(acc0[q], 0.f);
            v1[q] = fmaxf(acc1[q], 0.f);
        }

        if (t == T_STEPS - 1) {
            #pragma unroll
            for (int q = 0; q < 4; ++q) {
                hbuf[((size_t)t * B_SZ + b0 + mrow + q) * NR + n0] = v0[q];
                hbuf[((size_t)t * B_SZ + b0 + mrow + q) * NR + n1] = v1[q];
                hidout[(size_t)(b0 + mrow + q) * NR + n0] = v0[q];
                hidout[(size_t)(b0 + mrow + q) * NR + n1] = v1[q];
            }
            break;
        }

        // phase B: pack 4 cols -> u64 on l%4==0 lanes; LDS own half (untagged)
        //          + tagged IF export (self-flagging).
        {
            unsigned long long* Xh = Xg + (size_t)(pn * 2 + half) * 1024;
            const unsigned long long tagmask =
                tag ? 0x8000800080008000ULL : 0ULL;
            #pragma unroll
            for (int ct = 0; ct < 2; ++ct) {
                #pragma unroll
                for (int q = 0; q < 4; ++q) {
                    const float v = ct ? v1[q] : v0[q];
                    const float vo = __shfl_xor(v, 1, 64);
                    unsigned pk = (unsigned)f2bf(v) | ((unsigned)f2bf(vo) << 16);
                    const unsigned pk_hi = __shfl_xor(pk, 2, 64);
                    if ((l & 3) == 0) {
                        const int m = mrow + q;
                        const int c = w * 32 + ct * 16 + l15;     // own-half col, %4==0
                        const unsigned long long val =
                            (unsigned long long)pk | ((unsigned long long)pk_hi << 32);
                        const unsigned off = m * 1024 +
                            (((unsigned)(2 * (half * HALF_R + c))) ^ ((unsigned)((m & 7) << 4)));
                        *(unsigned long long*)(&Hl[pn][off]) = val;
                        __hip_atomic_store(Xh + m * 64 + (c >> 2), val | tagmask,
                                           __ATOMIC_RELAXED, __HIP_MEMORY_SCOPE_AGENT);
                    }
                }
            }
        }

        // barrier1: own-half LDS visible (lgkm only; exports stay in flight)
        asm volatile("s_waitcnt lgkmcnt(0)" ::: "memory");
        __builtin_amdgcn_sched_barrier(0);
        __builtin_amdgcn_s_barrier();
        __builtin_amdgcn_sched_barrier(0);

        // phase D: proj[t+1] prefetch, h[t] store, own-half recurrent for t+1
        #pragma unroll
        for (int q = 0; q < 4; ++q) {
            pj0[q] = hbuf[((size_t)(t + 1) * B_SZ + b0 + mrow + q) * NR + n0];
            pj1[q] = hbuf[((size_t)(t + 1) * B_SZ + b0 + mrow + q) * NR + n1];
        }
        #pragma unroll
        for (int q = 0; q < 4; ++q) {
            hbuf[((size_t)t * B_SZ + b0 + mrow + q) * NR + n0] = v0[q];
            hbuf[((size_t)t * B_SZ + b0 + mrow + q) * NR + n1] = v1[q];
        }
        acc0 = (f32x4){0.f, 0.f, 0.f, 0.f};
        acc1 = (f32x4){0.f, 0.f, 0.f, 0.f};
        if (half == 0) recur8<0>(&Hl[pn][0], Bh, acc0, acc1, l15, l4, swzA);
        else           recur8<8>(&Hl[pn][0], Bh, acc0, acc1, l15, l4, swzA);

        // phase E: poll partner's tagged lines (poll == pull), place in LDS
        {
            const int row = tid >> 5;
            const unsigned kk = (unsigned)((2 * tid) & 63);       // even u64 index
            const unsigned long long* src =
                Xg + (size_t)(pn * 2 + (half ^ 1)) * 1024 + row * 64 + kk;
            const unsigned et = (unsigned)tag;
            unsigned long long a, b;
            for (;;) {
                a = __hip_atomic_load(src,     __ATOMIC_RELAXED, __HIP_MEMORY_SCOPE_AGENT);
                b = __hip_atomic_load(src + 1, __ATOMIC_RELAXED, __HIP_MEMORY_SCOPE_AGENT);
                if ((((unsigned)(a >> 63)) == et) & (((unsigned)(b >> 63)) == et)) break;
            }
            if (tag) { a &= 0x7FFF7FFF7FFF7FFFULL; b &= 0x7FFF7FFF7FFF7FFFULL; }
            u64x2 dd; dd[0] = a; dd[1] = b;
            const unsigned off = row * 1024 +
                (((unsigned)((half ^ 1) * 512 + kk * 8)) ^ ((unsigned)((row & 7) << 4)));
            *(u64x2*)(&Hl[pn][off]) = dd;
        }
        #pragma unroll
        for (int q = 0; q < 4; ++q) { acc0[q] += pj0[q]; acc1[q] += pj1[q]; }

        // barrier2: pulled partner half visible in LDS
        asm volatile("s_waitcnt lgkmcnt(0)" ::: "memory");
        __builtin_amdgcn_sched_barrier(0);
        __builtin_amdgcn_s_barrier();
        __builtin_amdgcn_sched_barrier(0);
    }
}

// ---------------------------------------------------------------------------
// Output head: softmax(hidden @ Wo^T + bo). 256 blocks (one batch row) x 256.
// ---------------------------------------------------------------------------
__global__ __launch_bounds__(256) void rnn_out(
    const float* __restrict__ Wo, const float* __restrict__ bo,
    float* __restrict__ dout)
{
    const float* hidden = dout + (size_t)NO * B_SZ + (size_t)T_STEPS * B_SZ * NR;
    const int b = blockIdx.x;
    const int tid = threadIdx.x, w = tid >> 6, l = tid & 63;

    __shared__ float hid[NR];
    __shared__ float lg[NO];

    if (tid < 128) {
        *(float4*)(&hid[tid * 4]) = *(const float4*)(hidden + (size_t)b * NR + tid * 4);
    }
    __syncthreads();

    #pragma unroll 1
    for (int jj = 0; jj < 16; ++jj) {
        const int j = w * 16 + jj;
        const float4* wr = (const float4*)(Wo + (size_t)j * NR + l * 8);
        const float4 a = wr[0], c = wr[1];
        const float4 h0 = *(const float4*)(&hid[l * 8]);
        const float4 h1 = *(const float4*)(&hid[l * 8 + 4]);
        float s = a.x * h0.x + a.y * h0.y + a.z * h0.z + a.w * h0.w
                + c.x * h1.x + c.y * h1.y + c.z * h1.z + c.w * h1.w;
        #pragma unroll
        for (int d = 32; d > 0; d >>= 1) s += __shfl_xor(s, d, 64);
        if (l == 0) lg[j] = s + bo[j];
    }
    __syncthreads();

    if (tid < 64) {
        const float x = lg[tid];
        float mx = x;
        #pragma unroll
        for (int d = 32; d > 0; d >>= 1) mx = fmaxf(mx, __shfl_xor(mx, d, 64));
        const float e = __expf(x - mx);
        float sum = e;
        #pragma unroll
        for (int d = 32; d > 0; d >>= 1) sum += __shfl_xor(sum, d, 64);
        dout[(size_t)b * NO + tid] = e / sum;
    }
}

extern "C" void kernel_launch(void* const* d_in, const int* in_sizes, int n_in,
                              void* d_out, int out_size, void* d_ws, size_t ws_size,
                              hipStream_t stream) {
    const float* inputs = (const float*)d_in[0];
    const float* noise  = (const float*)d_in[1];
    const float* Wi     = (const float*)d_in[2];
    const float* bi     = (const float*)d_in[3];
    const float* Wrec   = (const float*)d_in[4];
    const float* Wo     = (const float*)d_in[5];
    const float* bo     = (const float*)d_in[6];
    float* out = (float*)d_out;

    // exchange buffer: 16 grp x 2 parity x 2 half x 16 rows x 64 u64 = 512 KB
    unsigned long long* Xbuf = (unsigned long long*)d_ws;

    float* proj = out + (size_t)NO * B_SZ;   // proj lives in the h-output region

    // zero tags each launch (kills cross-run stale-tag matches; ~free)
    hipMemsetAsync(d_ws, 0, 16 * 4096 * sizeof(unsigned long long), stream);
    proj_gemm<<<dim3(1024, 4), 256, 0, stream>>>(inputs, Wi, bi, noise, proj);
    rnn_scan<<<32, 512, 0, stream>>>(Wrec, out, Xbuf);
    rnn_out<<<256, 256, 0, stream>>>(Wo, bo, out);
}